// Round 7
// baseline (186.632 us; speedup 1.0000x reference)
//
#include <hip/hip_runtime.h>
#include <math.h>

#define N 512
#define NPAD(i) ((i) + ((i) >> 5))
#define FSZ 532
#define NCOL 257           // Hermitian: columns v = 0..256 only
// mask: (u-256)^2 + (v-256)^2 <= 51.2^2 (integer dist^2 exact in fp32)
#define RAD2 2621.44f
#define SQ2H 0.70710678f

// ---------------------------------------------------------------------------
// In-register 8-point DFT, natural order in/out.
// ---------------------------------------------------------------------------
__device__ __forceinline__ void dft8(float (&xr)[8], float (&xi)[8]) {
    float e0r = xr[0] + xr[4], e0i = xi[0] + xi[4];
    float e1r = xr[0] - xr[4], e1i = xi[0] - xi[4];
    float e2r = xr[2] + xr[6], e2i = xi[2] + xi[6];
    float e3r = xr[2] - xr[6], e3i = xi[2] - xi[6];
    float E0r = e0r + e2r, E0i = e0i + e2i;
    float E2r = e0r - e2r, E2i = e0i - e2i;
    float E1r = e1r + e3i, E1i = e1i - e3r;
    float E3r = e1r - e3i, E3i = e1i + e3r;
    float o0r = xr[1] + xr[5], o0i = xi[1] + xi[5];
    float o1r = xr[1] - xr[5], o1i = xi[1] - xi[5];
    float o2r = xr[3] + xr[7], o2i = xi[3] + xi[7];
    float o3r = xr[3] - xr[7], o3i = xi[3] - xi[7];
    float O0r = o0r + o2r, O0i = o0i + o2i;
    float O2r = o0r - o2r, O2i = o0i - o2i;
    float O1r = o1r + o3i, O1i = o1i - o3r;
    float O3r = o1r - o3i, O3i = o1i + o3r;
    float t1r = SQ2H * (O1r + O1i), t1i = SQ2H * (O1i - O1r);
    float t2r = O2i,                t2i = -O2r;
    float t3r = SQ2H * (O3i - O3r), t3i = -SQ2H * (O3r + O3i);
    xr[0] = E0r + O0r; xi[0] = E0i + O0i;
    xr[4] = E0r - O0r; xi[4] = E0i - O0i;
    xr[1] = E1r + t1r; xi[1] = E1i + t1i;
    xr[5] = E1r - t1r; xi[5] = E1i - t1i;
    xr[2] = E2r + t2r; xi[2] = E2i + t2i;
    xr[6] = E2r - t2r; xi[6] = E2i - t2i;
    xr[3] = E3r + t3r; xi[3] = E3i + t3i;
    xr[7] = E3r - t3r; xi[7] = E3i - t3i;
}

// ---------------------------------------------------------------------------
// TWO interleaved wave-level 512-pt FFTs via 6 radix-2 swizzle stages (K1).
// Lane l, reg k holds x[8*l + k] on input; out: reg t holds X[br6(l) + 64*t].
// ---------------------------------------------------------------------------
__device__ __forceinline__ void fft512_x2(float (&ar)[8], float (&ai)[8],
                                          float (&br)[8], float (&bi)[8],
                                          int l) {
#pragma unroll
    for (int half = 32; half >= 1; half >>= 1) {
        const int j = l & (half - 1);
        const float f = (float)j * (0.5f / (float)half);   // revolutions
        const float c = __builtin_amdgcn_cosf(f);
        const float s = __builtin_amdgcn_sinf(f);
        const bool up = (l & half) != 0;
        const float sgn = up ? -1.0f : 1.0f;
        const float wc  = up ? c : 1.0f;
        const float ws  = up ? s : 0.0f;
#pragma unroll
        for (int k = 0; k < 8; ++k) {
            float pr = __shfl_xor(ar[k], half);
            float pi = __shfl_xor(ai[k], half);
            float qr = __shfl_xor(br[k], half);
            float qi = __shfl_xor(bi[k], half);
            float tr = fmaf(sgn, ar[k], pr);
            float ti = fmaf(sgn, ai[k], pi);
            float ur = fmaf(sgn, br[k], qr);
            float ui = fmaf(sgn, bi[k], qi);
            ar[k] = tr * wc + ti * ws;
            ai[k] = ti * wc - tr * ws;
            br[k] = ur * wc + ui * ws;
            bi[k] = ui * wc - ur * ws;
        }
    }
    const int w = __brev((unsigned)l) >> 26;
#pragma unroll
    for (int k = 1; k < 8; ++k) {
        const float f = (float)(k * w) * (1.0f / 512.0f);
        const float c = __builtin_amdgcn_cosf(f);
        const float s = __builtin_amdgcn_sinf(f);
        float tr = ar[k] * c + ai[k] * s;
        float ti = ai[k] * c - ar[k] * s;
        ar[k] = tr; ai[k] = ti;
        float ur = br[k] * c + bi[k] * s;
        float ui = bi[k] * c - br[k] * s;
        br[k] = ur; bi[k] = ui;
    }
    dft8(ar, ai);
    dft8(br, bi);
}

// ---------------------------------------------------------------------------
// K1: grayscale + 2 packed row-pair FFTs per wave + Hermitian unpack +
// transposed write. 512 thr = 8 waves = 32 rows. Output buf[b][v][h].
// (unchanged from round 6)
// ---------------------------------------------------------------------------
__global__ __launch_bounds__(512) void k_gray_rowfft(
    const float* __restrict__ img, float2* __restrict__ buf) {
    __shared__ float sr[16][FSZ], si[16][FSZ];
    const int t = threadIdx.x, wv = t >> 6, l = t & 63;
    const int b = blockIdx.y, tile = blockIdx.x;
    const size_t plane = (size_t)N * N;
    const float* base = img + (size_t)b * 3 * plane;
    const int r0 = tile * 32 + 4 * wv;

    const float inv3 = 1.0f / 3.0f;
    auto loadgray = [&](const float* p, float (&g)[8]) {
        const float4* c0 = (const float4*)p;
        const float4* c1 = (const float4*)(p + plane);
        const float4* c2 = (const float4*)(p + 2 * plane);
#pragma unroll
        for (int q = 0; q < 2; ++q) {
            float4 a = c0[2 * l + q], bb = c1[2 * l + q], c = c2[2 * l + q];
            g[4 * q + 0] = (a.x + bb.x + c.x) * inv3;
            g[4 * q + 1] = (a.y + bb.y + c.y) * inv3;
            g[4 * q + 2] = (a.z + bb.z + c.z) * inv3;
            g[4 * q + 3] = (a.w + bb.w + c.w) * inv3;
        }
    };

    float arr[8], ari[8], brr[8], bri[8];
    loadgray(base + (size_t)(r0 + 0) * N, arr);
    loadgray(base + (size_t)(r0 + 1) * N, ari);
    loadgray(base + (size_t)(r0 + 2) * N, brr);
    loadgray(base + (size_t)(r0 + 3) * N, bri);

    fft512_x2(arr, ari, brr, bri, l);

    const int w = __brev((unsigned)l) >> 26;
    const int sA = 2 * wv, sB = 2 * wv + 1;
#pragma unroll
    for (int k = 0; k < 8; ++k) {
        int u = w + 64 * k;
        sr[sA][NPAD(u)] = arr[k]; si[sA][NPAD(u)] = ari[k];
        sr[sB][NPAD(u)] = brr[k]; si[sB][NPAD(u)] = bri[k];
    }
    __syncthreads();

    const int p = t & 15;
    const int h2 = 2 * p;
    const int slot = t >> 4;
    float2* ob = buf + (size_t)b * NCOL * N;
#pragma unroll
    for (int it = 0; it < 9; ++it) {
        int v = slot + 32 * it;
        if (v < NCOL) {
            int vn = (N - v) & (N - 1);
            float Zr  = sr[p][NPAD(v)],  Zi  = si[p][NPAD(v)];
            float Zr2 = sr[p][NPAD(vn)], Zi2 = si[p][NPAD(vn)];
            float4 o;
            o.x = 0.5f * (Zr + Zr2);
            o.y = 0.5f * (Zi - Zi2);
            o.z = 0.5f * (Zi + Zi2);
            o.w = 0.5f * (Zr2 - Zr);
            *(float4*)(&ob[(size_t)v * N + tile * 32 + h2]) = o;
        }
    }
}

// ---------------------------------------------------------------------------
// K2: column FFT as 512 = 8x8x8 — three in-register DFT8s + two wave-private
// LDS transposes (2 dependent LDS rounds instead of 6 swizzle rounds).
// 256 thr = 4 waves = 4 columns. Then masked/total magnitude reduction.
//
// n = 64a + 8b + c.  X[k0 + 8k1 + 64k2] =
//   DFT8_c( W512^{c(k0+8k1)} * DFT8_b( W64^{b*k0} * DFT8_a x[64a+8b+c] ) )
// Load: lane l=(b,c)=(l>>3,l&7), reg a = x[64a + l].
// T1 slot(k0,b,c) = 66*k0 + 8b + c  (write addr 66*k0 + l, lane-uniform offs)
// T2 slot(k1,k0,c) = 66*k1 + 8k0 + c (write addr 66*k1 + l)
// Final: lane l, reg k2 holds X[u], u = l + 64*k2 (natural order).
// ---------------------------------------------------------------------------
__global__ __launch_bounds__(256) void k_colfft_reduce(
    const float2* __restrict__ buf, float* __restrict__ acc) {
    __shared__ float2 lds[4][528];             // 8*66 per wave, wave-private
    __shared__ float red[8];
    const int t = threadIdx.x, wv = t >> 6, l = t & 63;
    const int b = blockIdx.y;
    const int v = blockIdx.x * 4 + wv;         // 0..259 (257.. dummies)
    const int vv = v > 256 ? 256 : v;

    const float2* col = buf + ((size_t)b * NCOL + vv) * N;
    float2* W = lds[wv];

    float xr[8], xi[8];
#pragma unroll
    for (int a = 0; a < 8; ++a) {              // reg a = x[64a + l], coalesced
        float2 z = col[64 * a + l];
        xr[a] = z.x; xi[a] = z.y;
    }

    // ---- round 1: DFT8 over a -> k0; twiddle W64^{b*k0} ----
    dft8(xr, xi);
    const int bb = l >> 3, cc = l & 7;
#pragma unroll
    for (int k0 = 1; k0 < 8; ++k0) {
        const float f = (float)(bb * k0) * (1.0f / 64.0f);
        const float c = __builtin_amdgcn_cosf(f);
        const float s = __builtin_amdgcn_sinf(f);
        float tr = xr[k0] * c + xi[k0] * s;    // * (c - i*s)
        float ti = xi[k0] * c - xr[k0] * s;
        xr[k0] = tr; xi[k0] = ti;
    }
    // ---- transpose 1 ----
#pragma unroll
    for (int k0 = 0; k0 < 8; ++k0)
        W[66 * k0 + l] = make_float2(xr[k0], xi[k0]);
    __builtin_amdgcn_wave_barrier();
#pragma unroll
    for (int bq = 0; bq < 8; ++bq) {           // lane: (k0=bb, c=cc); reg = b
        float2 z = W[66 * bb + 8 * bq + cc];
        xr[bq] = z.x; xi[bq] = z.y;
    }

    // ---- round 2: DFT8 over b -> k1; twiddle W512^{c*(k0 + 8*k1)} ----
    dft8(xr, xi);
#pragma unroll
    for (int k1 = 0; k1 < 8; ++k1) {
        const int e = cc * (bb + 8 * k1);      // <= 7*63 = 441
        const float f = (float)e * (1.0f / 512.0f);
        const float c = __builtin_amdgcn_cosf(f);
        const float s = __builtin_amdgcn_sinf(f);
        float tr = xr[k1] * c + xi[k1] * s;
        float ti = xi[k1] * c - xr[k1] * s;
        xr[k1] = tr; xi[k1] = ti;
    }
    // ---- transpose 2 ----
    __builtin_amdgcn_wave_barrier();
#pragma unroll
    for (int k1 = 0; k1 < 8; ++k1)
        W[66 * k1 + l] = make_float2(xr[k1], xi[k1]);
    __builtin_amdgcn_wave_barrier();
#pragma unroll
    for (int c2 = 0; c2 < 8; ++c2) {           // lane: (k1=l>>3, k0=l&7)
        float2 z = W[66 * (l >> 3) + 8 * (l & 7) + c2];
        xr[c2] = z.x; xi[c2] = z.y;
    }

    // ---- round 3: DFT8 over c -> k2.  u = l + 64*k2 ----
    dft8(xr, xi);

    const float wcol = (v == 0 || v == 256) ? 1.0f : (v < 256 ? 2.0f : 0.0f);
    const float dx = (float)(vv - 256);
    const float dx2 = dx * dx;
    float msum = 0.0f, tsum = 0.0f;
#pragma unroll
    for (int k2 = 0; k2 < 8; ++k2) {
        int u = l + 64 * k2;
        float mag = sqrtf(xr[k2] * xr[k2] + xi[k2] * xi[k2]);
        tsum += mag;
        float dy = (float)(u - 256);
        if (dy * dy + dx2 <= RAD2) msum += mag;
    }
    msum *= wcol; tsum *= wcol;
#pragma unroll
    for (int off = 32; off > 0; off >>= 1) {
        msum += __shfl_down(msum, off);
        tsum += __shfl_down(tsum, off);
    }
    if (l == 0) { red[wv * 2] = msum; red[wv * 2 + 1] = tsum; }
    __syncthreads();
    if (t == 0) {
        atomicAdd(&acc[b * 2 + 0], red[0] + red[2] + red[4] + red[6]);
        atomicAdd(&acc[b * 2 + 1], red[1] + red[3] + red[5] + red[7]);
    }
}

// K3: mean over batch of ratios.
__global__ void k_final(const float* __restrict__ acc,
                        float* __restrict__ out) {
    int t = threadIdx.x;                       // 64 threads
    float r = 0.0f;
    if (t < 32) r = acc[t * 2 + 0] / acc[t * 2 + 1];
#pragma unroll
    for (int off = 32; off > 0; off >>= 1) r += __shfl_down(r, off);
    if (t == 0) out[0] = r * (1.0f / 32.0f);
}

extern "C" void kernel_launch(void* const* d_in, const int* in_sizes, int n_in,
                              void* d_out, int out_size, void* d_ws,
                              size_t ws_size, hipStream_t stream) {
    const float* img = (const float*)d_in[0];
    float* out = (float*)d_out;

    float2* buf = (float2*)d_ws;               // [32][257][512] ~ 33.7MB
    const size_t buf_bytes = (size_t)32 * NCOL * N * sizeof(float2);
    float* acc = (float*)((char*)d_ws + buf_bytes);

    hipMemsetAsync(acc, 0, 64 * sizeof(float), stream);

    dim3 g1(N / 32, 32);                       // 16 row-tiles x 32 images
    k_gray_rowfft<<<g1, 512, 0, stream>>>(img, buf);

    dim3 g2((NCOL + 3) / 4, 32);               // 65 col-groups x 32 images
    k_colfft_reduce<<<g2, 256, 0, stream>>>(buf, acc);

    k_final<<<1, 64, 0, stream>>>(acc, out);
}

// Round 8
// 170.438 us; speedup vs baseline: 1.0950x; 1.0950x over previous
//
#include <hip/hip_runtime.h>
#include <math.h>

#define N 512
#define NPAD(i) ((i) + ((i) >> 5))
#define FSZ 532
#define NCOL 257           // Hermitian: columns v = 0..256 only
#define NG2 33             // K2 column-groups per image
// mask: (u-256)^2 + (v-256)^2 <= 51.2^2 (integer dist^2 exact in fp32)
#define RAD2 2621.44f
#define SQ2H 0.70710678f

// ---------------------------------------------------------------------------
// In-register 8-point DFT, natural order in/out.
// ---------------------------------------------------------------------------
__device__ __forceinline__ void dft8(float (&xr)[8], float (&xi)[8]) {
    float e0r = xr[0] + xr[4], e0i = xi[0] + xi[4];
    float e1r = xr[0] - xr[4], e1i = xi[0] - xi[4];
    float e2r = xr[2] + xr[6], e2i = xi[2] + xi[6];
    float e3r = xr[2] - xr[6], e3i = xi[2] - xi[6];
    float E0r = e0r + e2r, E0i = e0i + e2i;
    float E2r = e0r - e2r, E2i = e0i - e2i;
    float E1r = e1r + e3i, E1i = e1i - e3r;
    float E3r = e1r - e3i, E3i = e1i + e3r;
    float o0r = xr[1] + xr[5], o0i = xi[1] + xi[5];
    float o1r = xr[1] - xr[5], o1i = xi[1] - xi[5];
    float o2r = xr[3] + xr[7], o2i = xi[3] + xi[7];
    float o3r = xr[3] - xr[7], o3i = xi[3] - xi[7];
    float O0r = o0r + o2r, O0i = o0i + o2i;
    float O2r = o0r - o2r, O2i = o0i - o2i;
    float O1r = o1r + o3i, O1i = o1i - o3r;
    float O3r = o1r - o3i, O3i = o1i + o3r;
    float t1r = SQ2H * (O1r + O1i), t1i = SQ2H * (O1i - O1r);
    float t2r = O2i,                t2i = -O2r;
    float t3r = SQ2H * (O3i - O3r), t3i = -SQ2H * (O3r + O3i);
    xr[0] = E0r + O0r; xi[0] = E0i + O0i;
    xr[4] = E0r - O0r; xi[4] = E0i - O0i;
    xr[1] = E1r + t1r; xi[1] = E1i + t1i;
    xr[5] = E1r - t1r; xi[5] = E1i - t1i;
    xr[2] = E2r + t2r; xi[2] = E2i + t2i;
    xr[6] = E2r - t2r; xi[6] = E2i - t2i;
    xr[3] = E3r + t3r; xi[3] = E3i + t3i;
    xr[7] = E3r - t3r; xi[7] = E3i - t3i;
}

// ---------------------------------------------------------------------------
// TWO interleaved wave-level 512-pt FFTs (shared twiddles, overlapped
// latency). Lane l, reg k holds x[8*l + k] on input.
// Out: lane l, reg t holds X[br6(l) + 64*t].
// ---------------------------------------------------------------------------
__device__ __forceinline__ void fft512_x2(float (&ar)[8], float (&ai)[8],
                                          float (&br)[8], float (&bi)[8],
                                          int l) {
#pragma unroll
    for (int half = 32; half >= 1; half >>= 1) {
        const int j = l & (half - 1);
        const float f = (float)j * (0.5f / (float)half);   // revolutions
        const float c = __builtin_amdgcn_cosf(f);
        const float s = __builtin_amdgcn_sinf(f);
        const bool up = (l & half) != 0;
        const float sgn = up ? -1.0f : 1.0f;
        const float wc  = up ? c : 1.0f;
        const float ws  = up ? s : 0.0f;
#pragma unroll
        for (int k = 0; k < 8; ++k) {
            float pr = __shfl_xor(ar[k], half);
            float pi = __shfl_xor(ai[k], half);
            float qr = __shfl_xor(br[k], half);
            float qi = __shfl_xor(bi[k], half);
            float tr = fmaf(sgn, ar[k], pr);
            float ti = fmaf(sgn, ai[k], pi);
            float ur = fmaf(sgn, br[k], qr);
            float ui = fmaf(sgn, bi[k], qi);
            ar[k] = tr * wc + ti * ws;
            ai[k] = ti * wc - tr * ws;
            br[k] = ur * wc + ui * ws;
            bi[k] = ui * wc - ur * ws;
        }
    }
    const int w = __brev((unsigned)l) >> 26;
#pragma unroll
    for (int k = 1; k < 8; ++k) {
        const float f = (float)(k * w) * (1.0f / 512.0f);
        const float c = __builtin_amdgcn_cosf(f);
        const float s = __builtin_amdgcn_sinf(f);
        float tr = ar[k] * c + ai[k] * s;
        float ti = ai[k] * c - ar[k] * s;
        ar[k] = tr; ai[k] = ti;
        float ur = br[k] * c + bi[k] * s;
        float ui = bi[k] * c - br[k] * s;
        br[k] = ur; bi[k] = ui;
    }
    dft8(ar, ai);
    dft8(br, bi);
}

// ---------------------------------------------------------------------------
// K1: grayscale + 2 packed row-pair FFTs per wave + Hermitian unpack +
// transposed write. 512 thr = 8 waves = 32 rows. (round-6 verbatim)
// ---------------------------------------------------------------------------
__global__ __launch_bounds__(512) void k_gray_rowfft(
    const float* __restrict__ img, float2* __restrict__ buf) {
    __shared__ float sr[16][FSZ], si[16][FSZ];
    const int t = threadIdx.x, wv = t >> 6, l = t & 63;
    const int b = blockIdx.y, tile = blockIdx.x;
    const size_t plane = (size_t)N * N;
    const float* base = img + (size_t)b * 3 * plane;
    const int r0 = tile * 32 + 4 * wv;

    const float inv3 = 1.0f / 3.0f;
    auto loadgray = [&](const float* p, float (&g)[8]) {
        const float4* c0 = (const float4*)p;
        const float4* c1 = (const float4*)(p + plane);
        const float4* c2 = (const float4*)(p + 2 * plane);
#pragma unroll
        for (int q = 0; q < 2; ++q) {
            float4 a = c0[2 * l + q], bb = c1[2 * l + q], c = c2[2 * l + q];
            g[4 * q + 0] = (a.x + bb.x + c.x) * inv3;
            g[4 * q + 1] = (a.y + bb.y + c.y) * inv3;
            g[4 * q + 2] = (a.z + bb.z + c.z) * inv3;
            g[4 * q + 3] = (a.w + bb.w + c.w) * inv3;
        }
    };

    float arr[8], ari[8], brr[8], bri[8];
    loadgray(base + (size_t)(r0 + 0) * N, arr);
    loadgray(base + (size_t)(r0 + 1) * N, ari);
    loadgray(base + (size_t)(r0 + 2) * N, brr);
    loadgray(base + (size_t)(r0 + 3) * N, bri);

    fft512_x2(arr, ari, brr, bri, l);

    const int w = __brev((unsigned)l) >> 26;
    const int sA = 2 * wv, sB = 2 * wv + 1;
#pragma unroll
    for (int k = 0; k < 8; ++k) {
        int u = w + 64 * k;
        sr[sA][NPAD(u)] = arr[k]; si[sA][NPAD(u)] = ari[k];
        sr[sB][NPAD(u)] = brr[k]; si[sB][NPAD(u)] = bri[k];
    }
    __syncthreads();

    const int p = t & 15;
    const int h2 = 2 * p;
    const int slot = t >> 4;
    float2* ob = buf + (size_t)b * NCOL * N;
#pragma unroll
    for (int it = 0; it < 9; ++it) {
        int v = slot + 32 * it;
        if (v < NCOL) {
            int vn = (N - v) & (N - 1);
            float Zr  = sr[p][NPAD(v)],  Zi  = si[p][NPAD(v)];
            float Zr2 = sr[p][NPAD(vn)], Zi2 = si[p][NPAD(vn)];
            float4 o;
            o.x = 0.5f * (Zr + Zr2);
            o.y = 0.5f * (Zi - Zi2);
            o.z = 0.5f * (Zi + Zi2);
            o.w = 0.5f * (Zr2 - Zr);
            *(float4*)(&ob[(size_t)v * N + tile * 32 + h2]) = o;
        }
    }
}

// ---------------------------------------------------------------------------
// K2: 2 column FFTs per wave + masked/total reduction. NO global atomics:
// each block stores its partial pair to part[g][b]. 256 thr = 8 columns.
// ---------------------------------------------------------------------------
__global__ __launch_bounds__(256) void k_colfft_reduce(
    const float2* __restrict__ buf, float2* __restrict__ part) {
    __shared__ float red[8];
    const int t = threadIdx.x, wv = t >> 6, l = t & 63;
    const int b = blockIdx.y;
    const int v0 = blockIdx.x * 8 + 2 * wv;
    const int v1 = v0 + 1;
    const int c0 = v0 > 256 ? 256 : v0;
    const int c1 = v1 > 256 ? 256 : v1;

    const float4* colA = (const float4*)(buf + ((size_t)b * NCOL + c0) * N);
    const float4* colB = (const float4*)(buf + ((size_t)b * NCOL + c1) * N);
    float arr[8], ari[8], brr[8], bri[8];
#pragma unroll
    for (int q = 0; q < 4; ++q) {
        float4 zA = colA[4 * l + q];
        float4 zB = colB[4 * l + q];
        arr[2 * q] = zA.x; ari[2 * q] = zA.y;
        arr[2 * q + 1] = zA.z; ari[2 * q + 1] = zA.w;
        brr[2 * q] = zB.x; bri[2 * q] = zB.y;
        brr[2 * q + 1] = zB.z; bri[2 * q + 1] = zB.w;
    }

    fft512_x2(arr, ari, brr, bri, l);

    const float wA = (v0 == 0 || v0 == 256) ? 1.0f : (v0 < 256 ? 2.0f : 0.0f);
    const float wB = (v1 == 0 || v1 == 256) ? 1.0f : (v1 < 256 ? 2.0f : 0.0f);
    const float dxA = (float)(c0 - 256), dxA2 = dxA * dxA;
    const float dxB = (float)(c1 - 256), dxB2 = dxB * dxB;
    const int w = __brev((unsigned)l) >> 26;
    float msum = 0.0f, tsum = 0.0f;
#pragma unroll
    for (int k = 0; k < 8; ++k) {
        int u = w + 64 * k;
        float dy = (float)(u - 256);
        float dy2 = dy * dy;
        float magA = sqrtf(arr[k] * arr[k] + ari[k] * ari[k]) * wA;
        float magB = sqrtf(brr[k] * brr[k] + bri[k] * bri[k]) * wB;
        tsum += magA + magB;
        float m = 0.0f;
        if (dy2 + dxA2 <= RAD2) m += magA;
        if (dy2 + dxB2 <= RAD2) m += magB;
        msum += m;
    }
#pragma unroll
    for (int off = 32; off > 0; off >>= 1) {
        msum += __shfl_down(msum, off);
        tsum += __shfl_down(tsum, off);
    }
    if (l == 0) { red[wv * 2] = msum; red[wv * 2 + 1] = tsum; }
    __syncthreads();
    if (t == 0) {
        float m = red[0] + red[2] + red[4] + red[6];
        float s = red[1] + red[3] + red[5] + red[7];
        part[blockIdx.x * 32 + b] = make_float2(m, s);   // plain store
    }
}

// K3: reduce 33 partials per image, then mean of ratios.
__global__ void k_final(const float2* __restrict__ part,
                        float* __restrict__ out) {
    int t = threadIdx.x;                       // 64 threads
    float r = 0.0f;
    if (t < 32) {
        float m = 0.0f, s = 0.0f;
#pragma unroll
        for (int g = 0; g < NG2; ++g) {
            float2 p = part[g * 32 + t];
            m += p.x; s += p.y;
        }
        r = m / s;
    }
#pragma unroll
    for (int off = 32; off > 0; off >>= 1) r += __shfl_down(r, off);
    if (t == 0) out[0] = r * (1.0f / 32.0f);
}

extern "C" void kernel_launch(void* const* d_in, const int* in_sizes, int n_in,
                              void* d_out, int out_size, void* d_ws,
                              size_t ws_size, hipStream_t stream) {
    const float* img = (const float*)d_in[0];
    float* out = (float*)d_out;

    float2* buf = (float2*)d_ws;               // [32][257][512] ~ 33.7MB
    const size_t buf_bytes = (size_t)32 * NCOL * N * sizeof(float2);
    float2* part = (float2*)((char*)d_ws + buf_bytes);  // [33][32] pairs

    dim3 g1(N / 32, 32);                       // 16 row-tiles x 32 images
    k_gray_rowfft<<<g1, 512, 0, stream>>>(img, buf);

    dim3 g2((NCOL + 7) / 8, 32);               // 33 col-groups x 32 images
    k_colfft_reduce<<<g2, 256, 0, stream>>>(buf, part);

    k_final<<<1, 64, 0, stream>>>(part, out);
}